// Round 10
// baseline (614.737 us; speedup 1.0000x reference)
//
#include <hip/hip_runtime.h>
#include <math.h>

#define DD 64
#define BIGF 1.0e9f

// uniform-lane broadcast via v_readlane (no DS pipe)
__device__ __forceinline__ float bcastf(float x, int lane) {
    return __builtin_bit_cast(float, __builtin_amdgcn_readlane(__builtin_bit_cast(int, x), lane));
}
__device__ __forceinline__ int bcasti(int x, int lane) {
    return __builtin_amdgcn_readlane(x, lane);
}

// full-wave64 min via DPP (pure VALU): row_shr 1/2/4/8 + row_bcast15/31.
__device__ __forceinline__ float wave_min64(float x) {
#define STEPD(ctrl)                                                                \
    {                                                                              \
        int _t = __builtin_amdgcn_update_dpp(__builtin_bit_cast(int, x),           \
                                             __builtin_bit_cast(int, x),           \
                                             ctrl, 0xF, 0xF, false);               \
        x = fminf(x, __builtin_bit_cast(float, _t));                               \
    }
    STEPD(0x111)  // row_shr:1
    STEPD(0x112)  // row_shr:2
    STEPD(0x114)  // row_shr:4
    STEPD(0x118)  // row_shr:8
    STEPD(0x142)  // row_bcast:15
    STEPD(0x143)  // row_bcast:31
#undef STEPD
    return bcastf(x, 63);
}

// ---- fast f64 log (r9, proven absmax 0.0): table + degree-6 log1p ----
__device__ __forceinline__ double fast_log(double d, const double2* __restrict__ tbl) {
    long long bits = __double_as_longlong(d);
    int e = (int)(bits >> 52) - 1023;
    double m = __longlong_as_double((bits & 0x000FFFFFFFFFFFFFLL) | 0x3FF0000000000000LL);
    int idx = (int)(bits >> 45) & 127;
    double2 t = tbl[idx];                 // t.x = inv_c (rounded), t.y = -log(inv_c)
    double r  = fma(m, t.x, -1.0);
    double r2 = r * r;
    double q = fma(r, -1.0 / 6.0, 0.2);
    q = fma(q, r, -0.25);
    q = fma(q, r, 1.0 / 3.0);
    q = fma(q, r, -0.5);
    double res = fma(q, r2, r);           // log1p(r)
    return fma((double)e, 0.69314718055994530942, t.y + res);
}

// ---- Stage: cost = -(gamma + gumbel), gumbel = -log(-log(clip(u))) ----
__global__ __launch_bounds__(256) void stage_kernel(
    const float* __restrict__ gamma,
    const float* __restrict__ uin,
    float* __restrict__ cost,
    int total4)
{
    __shared__ double2 tbl[128];
    {
        int t = threadIdx.x;
        if (t < 128) {
            double c = 1.0 + (double)(2 * t + 1) * (1.0 / 256.0);
            double inv = 1.0 / c;
            tbl[t].x = inv;
            tbl[t].y = -log(inv);
        }
    }
    __syncthreads();

    const float lo = 1e-20f;
    const float hi = (float)(1.0 - 1e-7);
    const int stride = gridDim.x * blockDim.x;

    for (int idx = blockIdx.x * blockDim.x + threadIdx.x; idx < total4; idx += stride) {
        float4 u4 = ((const float4*)uin)[idx];
        int e = idx << 2;
        const float4 g4 = *(const float4*)(gamma + (e & (DD * DD - 1)));

        float uu[4] = {u4.x, u4.y, u4.z, u4.w};
        float gg[4] = {g4.x, g4.y, g4.z, g4.w};
        float rr[4];
#pragma unroll
        for (int k = 0; k < 4; ++k) {
            float x = fminf(fmaxf(uu[k], lo), hi);
            float inner = (float)fast_log((double)x, tbl);
            float outer = (float)fast_log((double)(-inner), tbl);
            float sc = gg[k] + (-outer);
            rr[k] = -sc;
        }
        float4 r4 = {rr[0], rr[1], rr[2], rr[3]};
        ((float4*)cost)[idx] = r4;
    }
}

// ---- persistent ILP-2 JV solver ----
// One wave per block; each wave holds TWO independent samples (A,B) whose
// STEP dependency chains share one basic block and interleave. When a sample
// finishes, the wave writes its one-hot and pulls a fresh id from a global
// atomic counter (dynamic rebalancing; no pair-spin, no static-drain).
// Per-sample arithmetic is the bit-exact r6..r9 trajectory, unchanged.

#define GRAB(S) do {                                                         \
    unsigned t = 0;                                                          \
    if (l == 0) t = atomicAdd(counter, 1u);                                  \
    int id = bcasti((int)t, 0);                                              \
    done##S = (id >= nsamp);                                                 \
    cb##S = cost + (size_t)(done##S ? 0 : id) * (DD * DD);                   \
    v##S = 0.f; ud##S = 0.f; p##S = 0; i##S = 0;                             \
    minv##S = BIGF; way##S = 0; used##S = false; inTree##S = (l == 0);       \
    j0##S = 0; pj1##S = 1;                                                   \
    c##S = cb##S[l]; u##S = 0.f;                                             \
} while (0)

// One search iteration (branchless; clamped unconditional prefetch).
// un is read BEFORE ud += di: row pj1 is not yet inTree (exactness, r6).
#define STEP(S) do {                                                         \
    float cur = (c##S - u##S) - v##S;                                        \
    bool bett = (!used##S) && (cur < minv##S);                               \
    minv##S = bett ? cur : minv##S;                                          \
    way##S  = bett ? j0##S : way##S;                                         \
    float delta = wave_min64(minv##S);                                       \
    unsigned long long tie = __ballot(minv##S == delta);                     \
    int j1 = (int)__ffsll(tie);                                              \
    j1 = __builtin_amdgcn_readfirstlane(j1);                                 \
    pj1##S = bcasti(p##S, j1 - 1);                                           \
    int nrow = (pj1##S != 0 ? pj1##S : 1) - 1;                               \
    float cn = cb##S[nrow * DD + l];                                         \
    float un = bcastf(ud##S, nrow);                                          \
    float du = used##S ? delta : 0.0f;                                       \
    float di = inTree##S ? delta : 0.0f;                                     \
    ud##S += di;                                                             \
    v##S  -= du;                                                             \
    minv##S -= (delta - du);                                                 \
    bool isj1 = (l == (j1 - 1));                                             \
    used##S = used##S || isj1;                                               \
    minv##S = isj1 ? BIGF : minv##S;                                         \
    inTree##S = inTree##S || (l == (pj1##S - 1));                            \
    j0##S = j1;                                                              \
    c##S = cn; u##S = un;                                                    \
} while (0)

#define AUG(S) do {                                                          \
    int jj = j0##S;                                                          \
    while (jj != 0) {                                                        \
        int jn = bcasti(way##S, jj - 1);                                     \
        int pn = (jn == 0) ? (i##S + 1) : bcasti(p##S, jn - 1);              \
        if (l == (jj - 1)) p##S = pn;                                        \
        jj = jn;                                                             \
    }                                                                        \
} while (0)

#define ROWNEXT(S) do {                                                      \
    ++i##S;                                                                  \
    if (i##S >= DD) {                                                        \
        const int prow = p##S - 1;                                           \
        _Pragma("nounroll")                                                  \
        for (int r = 0; r < DD; ++r)                                         \
            cb##S[r * DD + l] = (prow == r) ? 1.0f : 0.0f;                   \
        GRAB(S);                                                             \
    } else {                                                                 \
        minv##S = BIGF; way##S = 0; used##S = false;                         \
        inTree##S = (l == i##S); j0##S = 0;                                  \
        c##S = cb##S[i##S * DD + l];                                         \
        u##S = bcastf(ud##S, i##S);                                          \
    }                                                                        \
} while (0)

__global__ __launch_bounds__(64, 4) void lap64_persist(
    float* __restrict__ cost,
    unsigned* __restrict__ counter,
    int nsamp)
{
    const int l = threadIdx.x;

    float vA, udA, minvA, cA, uA;  int pA, wayA, j0A, iA, pj1A;
    bool usedA, inTreeA, doneA;    float* cbA;
    float vB, udB, minvB, cB, uB;  int pB, wayB, j0B, iB, pj1B;
    bool usedB, inTreeB, doneB;    float* cbB;

    GRAB(A);
    GRAB(B);

    while (!(doneA && doneB)) {
        STEP(A);
        STEP(B);
        if (!doneA && pj1A == 0) { AUG(A); ROWNEXT(A); }
        if (!doneB && pj1B == 0) { AUG(B); ROWNEXT(B); }
    }
}

extern "C" void kernel_launch(void* const* d_in, const int* in_sizes, int n_in,
                              void* d_out, int out_size, void* d_ws, size_t ws_size,
                              hipStream_t stream) {
    const float* gamma = (const float*)d_in[0];
    const float* u     = (const float*)d_in[1];
    float* out = (float*)d_out;
    const int nsamp = in_sizes[1] / (DD * DD);
    const int total4 = nsamp * DD * DD / 4;

    // work-queue counter lives in d_ws; must be zeroed every launch (graph-safe)
    hipMemsetAsync(d_ws, 0, sizeof(unsigned), stream);
    stage_kernel<<<dim3(4096), dim3(256), 0, stream>>>(gamma, u, out, total4);
    lap64_persist<<<dim3(3584), dim3(64), 0, stream>>>(out, (unsigned*)d_ws, nsamp);
}

// Round 11
// 353.825 us; speedup vs baseline: 1.7374x; 1.7374x over previous
//
#include <hip/hip_runtime.h>
#include <math.h>

#define DD 64
#define BIGF 1.0e9f

// uniform-lane broadcast via v_readlane (no DS pipe)
__device__ __forceinline__ float bcastf(float x, int lane) {
    return __builtin_bit_cast(float, __builtin_amdgcn_readlane(__builtin_bit_cast(int, x), lane));
}
__device__ __forceinline__ int bcasti(int x, int lane) {
    return __builtin_amdgcn_readlane(x, lane);
}

// full-wave64 min via DPP (pure VALU): row_shr 1/2/4/8 + row_bcast15/31.
// bound_ctrl=false: invalid source lanes keep old value (harmless for min).
__device__ __forceinline__ float wave_min64(float x) {
#define STEPD(ctrl)                                                                \
    {                                                                              \
        int _t = __builtin_amdgcn_update_dpp(__builtin_bit_cast(int, x),           \
                                             __builtin_bit_cast(int, x),           \
                                             ctrl, 0xF, 0xF, false);               \
        x = fminf(x, __builtin_bit_cast(float, _t));                               \
    }
    STEPD(0x111)  // row_shr:1
    STEPD(0x112)  // row_shr:2
    STEPD(0x114)  // row_shr:4
    STEPD(0x118)  // row_shr:8
    STEPD(0x142)  // row_bcast:15
    STEPD(0x143)  // row_bcast:31
#undef STEPD
    return bcastf(x, 63);
}

// ---- fast f64 log (r9, proven absmax 0.0): table + degree-6 log1p ----
__device__ __forceinline__ double fast_log(double d, const double2* __restrict__ tbl) {
    long long bits = __double_as_longlong(d);
    int e = (int)(bits >> 52) - 1023;
    double m = __longlong_as_double((bits & 0x000FFFFFFFFFFFFFLL) | 0x3FF0000000000000LL);
    int idx = (int)(bits >> 45) & 127;
    double2 t = tbl[idx];                 // t.x = inv_c (rounded), t.y = -log(inv_c)
    double r  = fma(m, t.x, -1.0);
    double r2 = r * r;
    double q = fma(r, -1.0 / 6.0, 0.2);
    q = fma(q, r, -0.25);
    q = fma(q, r, 1.0 / 3.0);
    q = fma(q, r, -0.5);
    double res = fma(q, r2, r);           // log1p(r)
    return fma((double)e, 0.69314718055994530942, t.y + res);
}

// ---- Stage: cost = -(gamma + gumbel), gumbel = -log(-log(clip(u))) ----
__global__ __launch_bounds__(256) void stage_kernel(
    const float* __restrict__ gamma,
    const float* __restrict__ uin,
    float* __restrict__ cost,
    int total4)
{
    __shared__ double2 tbl[128];
    {
        int t = threadIdx.x;
        if (t < 128) {
            double c = 1.0 + (double)(2 * t + 1) * (1.0 / 256.0);
            double inv = 1.0 / c;
            tbl[t].x = inv;
            tbl[t].y = -log(inv);
        }
    }
    __syncthreads();

    const float lo = 1e-20f;
    const float hi = (float)(1.0 - 1e-7);
    const int stride = gridDim.x * blockDim.x;

    for (int idx = blockIdx.x * blockDim.x + threadIdx.x; idx < total4; idx += stride) {
        float4 u4 = ((const float4*)uin)[idx];
        int e = idx << 2;
        const float4 g4 = *(const float4*)(gamma + (e & (DD * DD - 1)));

        float uu[4] = {u4.x, u4.y, u4.z, u4.w};
        float gg[4] = {g4.x, g4.y, g4.z, g4.w};
        float rr[4];
#pragma unroll
        for (int k = 0; k < 4; ++k) {
            float x = fminf(fmaxf(uu[k], lo), hi);
            float inner = (float)fast_log((double)x, tbl);
            float outer = (float)fast_log((double)(-inner), tbl);
            float sc = gg[k] + (-outer);
            rr[k] = -sc;
        }
        float4 r4 = {rr[0], rr[1], rr[2], rr[3]};
        ((float4*)cost)[idx] = r4;
    }
}

// ---- LAP: 256-thread blocks = 4 independent waves, 1 sample each. ----
// Lane l owns column j=l+1 state (v,minv,way,p,used) and row r=l+1 dual u.
// Literal f32 replication of the reference JV trajectory:
//   masked = where(used, BIG, minv); delta = min(masked);
//   j1 = first index with masked == delta;
//   u[tree rows] += delta; v = where(used, v-delta, v);
//   minv = where(used, minv, minv-delta).
// u[i0] prefetch reads lane pj1-1 BEFORE its ud update (row pj1 not yet in
// tree - exactness proven r6). All loops unroll-disabled to keep VGPRs low
// (r3..r7 pinned at 4 waves/SIMD; suspected unroll-driven 128-reg tier).
__global__ __launch_bounds__(256, 8) void lap64_kernel(float* __restrict__ cost, int nsamp)
{
    const int l = threadIdx.x & 63;
    const int b = blockIdx.x * 4 + (threadIdx.x >> 6);
    if (b >= nsamp) return;
    float* cb = cost + (size_t)b * (DD * DD);

    float v  = 0.0f;  // v[l+1]
    float ud = 0.0f;  // u[l+1]
    int   p  = 0;     // p[l+1] (1-based row matched to column l+1; 0 = none)

#pragma clang loop unroll(disable)
    for (int i = 0; i < DD; ++i) {
        float minv = BIGF;
        int   way  = 0;
        bool  used = false;
        bool  inTree = (l == i);      // row i+1 enters tree via virtual col 0
        int   j0 = 0;
        float c    = cb[i * DD + l];  // row i0-1 = i
        float u_i0 = bcastf(ud, i);   // u[i+1]

#pragma clang loop unroll(disable)
        for (int it = 0; it <= DD; ++it) {
            float cur = (c - u_i0) - v;            // ((cost - u) - v), as reference
            bool cc = (!used) && (cur < minv);
            minv = cc ? cur : minv;
            way  = cc ? j0  : way;

            float masked = used ? BIGF : minv;     // ref: where(used, BIG, minv)
            float delta = wave_min64(masked);
            unsigned long long tie = __ballot(masked == delta);
            int j1 = (int)__builtin_ctzll(tie) + 1; // first-index tie-break (scalar)
            int pj1 = bcasti(p, j1 - 1);

            // prefetch next row + next u[i0] (lane pj1-1 not yet inTree)
            if (pj1 != 0) {
                c    = cb[(pj1 - 1) * DD + l];
                u_i0 = bcastf(ud, pj1 - 1);
            }

            // dual updates: literal where()-forms
            float udn = ud + delta;
            float vn  = v - delta;
            float mn  = minv - delta;
            ud   = inTree ? udn : ud;
            v    = used   ? vn  : v;
            minv = used   ? minv : mn;

            used = used || (l == (j1 - 1));
            j0 = j1;
            if (pj1 == 0) break;
            inTree = inTree || (l == (pj1 - 1));
        }

        // ---- augment along way[] chain ----
#pragma clang loop unroll(disable)
        while (j0 != 0) {
            int jn = bcasti(way, j0 - 1);
            int pn = (jn == 0) ? (i + 1) : bcasti(p, jn - 1);
            if (l == (j0 - 1)) p = pn;
            j0 = jn;
        }
    }

    // ---- overwrite cost region with one-hot permutation: out[b][p-1][l] = 1 ----
    const int prow = p - 1;
#pragma clang loop unroll(disable)
    for (int r = 0; r < DD; ++r) {
        cb[r * DD + l] = (prow == r) ? 1.0f : 0.0f;
    }
}

extern "C" void kernel_launch(void* const* d_in, const int* in_sizes, int n_in,
                              void* d_out, int out_size, void* d_ws, size_t ws_size,
                              hipStream_t stream) {
    const float* gamma = (const float*)d_in[0];
    const float* u     = (const float*)d_in[1];
    float* out = (float*)d_out;
    const int nsamp = in_sizes[1] / (DD * DD);
    const int total4 = nsamp * DD * DD / 4;

    stage_kernel<<<dim3(4096), dim3(256), 0, stream>>>(gamma, u, out, total4);
    lap64_kernel<<<dim3((nsamp + 3) / 4), dim3(256), 0, stream>>>(out, nsamp);
}